// Round 1
// 352.585 us; speedup vs baseline: 1.0534x; 1.0534x over previous
//
#include <hip/hip_runtime.h>
#include <math.h>

#define NN 8
#define RR 256
#define CD 64      // in/out channel dim
#define MM 32      // kept modes per dim
#define KHN 64     // 2*MM kh values (rows 0..31 and 224..255)
#define KWN 32

#define ANG 0.024543692606170259f  // 2*pi/256
#define INVN (1.0f / 65536.0f)     // ortho norm, folded into k3 weights

typedef __attribute__((ext_vector_type(4))) float f32x4;
typedef __attribute__((ext_vector_type(8))) short short8;
typedef unsigned short u16;

__device__ inline u16 f2bf(float f) {
    union { float f; unsigned u; } v; v.f = f;
    unsigned r = v.u + 0x7FFF + ((v.u >> 16) & 1);
    return (u16)(r >> 16);
}
__device__ inline unsigned pack2(float a, float b) {
    return (unsigned)f2bf(a) | ((unsigned)f2bf(b) << 16);
}
// bijective LDS block swizzle key: spreads banks for both transpose-writes
// (lanes vary row high bits) and ds_read_b128 fragment reads (lanes vary row low bits)
__device__ inline int swkey(int row) { return (row & 7) ^ ((row >> 3) & 7); }

// ---------------- K0: build twiddle operand tables (bf16) -------------------
// A2[128 x 512]: k2 A.  rows: kh' (0..63 R, 64..127 I); cols: k (h for xR | h for xI)
// A4[512 x 128]: k4 A.  rows: (h R 0..255, h I 256..511); cols: (khIdx xR | khIdx xI)
// T1[64 x 256]:  k1 A.  rows kw' (cos rows 0..31, -sin rows 32..63); cols w
// T5[256 x 64]:  k5 A twiddle cols. row w; col c: c==0->1, c<32->2cos, c==32->0, else->-2sin
// RWT[64 x 64]:  res_w^T in bf16 (row o, col i)
__global__ __launch_bounds__(256) void k0_tables(u16* __restrict__ A2g,
                                                 u16* __restrict__ A4g,
                                                 u16* __restrict__ T1g,
                                                 u16* __restrict__ T5g,
                                                 const float* __restrict__ res_w,
                                                 u16* __restrict__ RWTg) {
    int gid = blockIdx.x * 256 + threadIdx.x;   // 0..65535
    {
        int r = gid >> 9, k = gid & 511;
        int khIdx = r & 63, part = r >> 6;
        int kh = (khIdx < 32) ? khIdx : 192 + khIdx;
        int h = k & 255, kpart = k >> 8;
        float s, c;
        __sincosf((float)((kh * h) & 255) * ANG, &s, &c);
        float v = (part == 0) ? ((kpart == 0) ? c : s)
                              : ((kpart == 0) ? -s : c);
        A2g[gid] = f2bf(v);
    }
    {
        int r = gid >> 7, k = gid & 127;
        int h = r & 255, part = r >> 8;
        int khIdx = k & 63, kpart = k >> 6;
        int kh = (khIdx < 32) ? khIdx : 192 + khIdx;
        float s, c;
        __sincosf((float)((kh * h) & 255) * ANG, &s, &c);
        float v = (part == 0) ? ((kpart == 0) ? c : -s)
                              : ((kpart == 0) ? s : c);
        A4g[gid] = f2bf(v);
    }
    if (gid < 16384) {
        {
            int r = gid >> 8, w = gid & 255;
            float s, c;
            if (r < 32) { __sincosf((float)((r * w) & 255) * ANG, &s, &c); T1g[gid] = f2bf(c); }
            else        { __sincosf((float)(((r - 32) * w) & 255) * ANG, &s, &c); T1g[gid] = f2bf(-s); }
        }
        {
            int w = gid >> 6, c = gid & 63;
            float v;
            if (c == 0) v = 1.0f;
            else if (c < 32) { float s, co; __sincosf((float)((c * w) & 255) * ANG, &s, &co); v = 2.0f * co; }
            else if (c == 32) v = 0.0f;
            else { float s, co; __sincosf((float)(((c - 32) * w) & 255) * ANG, &s, &co); v = -2.0f * s; }
            T5g[gid] = f2bf(v);
        }
    }
    if (gid < 4096) {
        int o = gid >> 6, i = gid & 63;
        RWTg[gid] = f2bf(res_w[i * 64 + o]);
    }
}

// ---------------- K1: real DFT along w as bf16 MFMA GEMM ----------------
// per nh: [kw'(64) x c(64)] = T1[64x256] @ x^T[256x64]
// A-frags straight from L2 (T1g). Bt[c][w] swizzled. Out layout [n][kw][h][c].
__global__ __launch_bounds__(256) void k1_dft_w(const float* __restrict__ x,
                                                const u16* __restrict__ T1g,
                                                u16* __restrict__ X1R,
                                                u16* __restrict__ X1I) {
    __shared__ __align__(16) u16 Bt[64 * 256];   // 32 KB
    unsigned* B32 = (unsigned*)Bt;
    int t = threadIdx.x;
    int nh = blockIdx.x;
    const float* xr = x + (size_t)nh * (RR * CD);
#pragma unroll
    for (int it = 0; it < 8; ++it) {
        int idx = t + it * 256;            // 0..2047
        int q = idx >> 4;                  // w-pair 0..127
        int c0 = (idx & 15) * 4;
        float4 f0 = *(const float4*)&xr[(2 * q) * 64 + c0];
        float4 f1 = *(const float4*)&xr[(2 * q + 1) * 64 + c0];
        B32[(c0 + 0) * 128 + (q ^ (swkey(c0 + 0) << 2))] = pack2(f0.x, f1.x);
        B32[(c0 + 1) * 128 + (q ^ (swkey(c0 + 1) << 2))] = pack2(f0.y, f1.y);
        B32[(c0 + 2) * 128 + (q ^ (swkey(c0 + 2) << 2))] = pack2(f0.z, f1.z);
        B32[(c0 + 3) * 128 + (q ^ (swkey(c0 + 3) << 2))] = pack2(f0.w, f1.w);
    }
    __syncthreads();
    int wv = t >> 6, l = t & 63, lm = l & 15, lq = l >> 4;
    f32x4 acc[4];
#pragma unroll
    for (int nt = 0; nt < 4; ++nt) { f32x4 z = {0.f, 0.f, 0.f, 0.f}; acc[nt] = z; }
#pragma unroll
    for (int ks = 0; ks < 8; ++ks) {
        short8 a = *(const short8*)&T1g[(wv * 16 + lm) * 256 + ks * 32 + lq * 8];
#pragma unroll
        for (int nt = 0; nt < 4; ++nt) {
            int c = nt * 16 + lm;
            short8 b = *(const short8*)&Bt[c * 256 + ((ks * 32 + lq * 8) ^ (swkey(c) << 3))];
            acc[nt] = __builtin_amdgcn_mfma_f32_16x16x32_bf16(a, b, acc[nt], 0, 0, 0);
        }
    }
    int n = nh >> 8, h = nh & 255;
#pragma unroll
    for (int nt = 0; nt < 4; ++nt)
#pragma unroll
        for (int r = 0; r < 4; ++r) {
            int kwp = wv * 16 + lq * 4 + r;
            int cc = nt * 16 + lm;
            u16 v = f2bf(acc[nt][r]);
            if (kwp < 32) X1R[(((size_t)n * 32 + kwp) * 256 + h) * 64 + cc] = v;
            else          X1I[(((size_t)n * 32 + (kwp - 32)) * 256 + h) * 64 + cc] = v;
        }
}

// ---------------- K2: complex DFT along h as bf16 MFMA GEMM ----------------
// per (n,kw): [128 kh'-rows x 64 c] = A2[128x512] @ B[512x64]
// 512 threads (8 waves). A-frags from L2. B double-buffered 16 KB chunks, swizzled.
__global__ __launch_bounds__(512) void k2_dft_h(const u16* __restrict__ X1R,
                                                const u16* __restrict__ X1I,
                                                const u16* __restrict__ A2g,
                                                float2* __restrict__ X2) {
    __shared__ __align__(16) u16 Bs[2][64 * 128];   // 2 x 16 KB
    int t = threadIdx.x;
    int n = blockIdx.x >> 5, kw = blockIdx.x & 31;
    const u16* baseR = X1R + ((size_t)n * 32 + kw) * (256 * 64);
    const u16* baseI = X1I + ((size_t)n * 32 + kw) * (256 * 64);
    int wv = t >> 6, l = t & 63, lm = l & 15, lq = l >> 4;
    f32x4 acc[4];
#pragma unroll
    for (int nt = 0; nt < 4; ++nt) { f32x4 z = {0.f, 0.f, 0.f, 0.f}; acc[nt] = z; }

    auto stage = [&](int ck, int buf) {
        const u16* src = ((ck < 2) ? baseR : baseI) + (size_t)(ck & 1) * (128 * 64);
        u16* B = Bs[buf];
#pragma unroll
        for (int it = 0; it < 2; ++it) {
            int idx = t + it * 512;        // 0..1023
            int hh = idx >> 3, g = idx & 7;
            short8 v = *(const short8*)&src[hh * 64 + g * 8];
#pragma unroll
            for (int j = 0; j < 8; ++j) {
                int c = g * 8 + j;
                B[c * 128 + (hh ^ (swkey(c) << 3))] = (u16)v[j];
            }
        }
    };
    stage(0, 0);
    __syncthreads();
    for (int ck = 0; ck < 4; ++ck) {
        if (ck < 3) stage(ck + 1, (ck + 1) & 1);
        const u16* B = Bs[ck & 1];
#pragma unroll
        for (int ks = 0; ks < 4; ++ks) {
            short8 a = *(const short8*)&A2g[(wv * 16 + lm) * 512 + ck * 128 + ks * 32 + lq * 8];
#pragma unroll
            for (int nt = 0; nt < 4; ++nt) {
                int c = nt * 16 + lm;
                short8 b = *(const short8*)&B[c * 128 + ((ks * 32 + lq * 8) ^ (swkey(c) << 3))];
                acc[nt] = __builtin_amdgcn_mfma_f32_16x16x32_bf16(a, b, acc[nt], 0, 0, 0);
            }
        }
        __syncthreads();
    }
#pragma unroll
    for (int nt = 0; nt < 4; ++nt)
#pragma unroll
        for (int r = 0; r < 4; ++r) {
            int m = wv * 16 + lq * 4 + r;     // 0..127
            int c = nt * 16 + lm;
            float* dst = (float*)&X2[(((size_t)n * 64 + (m & 63)) * 32 + kw) * 64 + c];
            dst[m >> 6] = acc[nt][r];
        }
}

// ---------------- K3: per-mode complex 64x64 channel matmul (fp32) ---------
// output packed bf16 (R,I) in u32, layout [n][kw][khl][o] (K4-friendly)
__global__ __launch_bounds__(256) void k3_spectral(const float2* __restrict__ X2,
                                                   const float* __restrict__ w0,
                                                   const float* __restrict__ w1,
                                                   unsigned* __restrict__ X3b) {
    __shared__ float2 WsP[4096];
    __shared__ float2 XsP[512];
    int t = threadIdx.x;
    int khIdx = blockIdx.x >> 5;
    int kw = blockIdx.x & 31;
    const float* wsrc = (khIdx < 32)
        ? (w0 + (size_t)(khIdx * 32 + kw) * (64 * 64 * 2))
        : (w1 + (size_t)((khIdx - 32) * 32 + kw) * (64 * 64 * 2));
    const float4* wsrc4 = (const float4*)wsrc;
#pragma unroll
    for (int k = 0; k < 8; ++k) {
        int idx = t + k * 256;             // 0..2047 float4 = 2 complex
        float4 v = wsrc4[idx];
        WsP[2 * idx]     = make_float2(v.x * INVN, v.y * INVN);
        WsP[2 * idx + 1] = make_float2(v.z * INVN, v.w * INVN);
    }
#pragma unroll
    for (int k = 0; k < 2; ++k) {
        int id2 = t + k * 256;
        int n = id2 >> 6, c = id2 & 63;
        XsP[id2] = X2[(((size_t)n * KHN + khIdx) * KWN + kw) * CD + c];
    }
    __syncthreads();
    int o = t & 63;
    int ng = t >> 6;
#pragma unroll
    for (int p = 0; p < 2; ++p) {
        int n = ng + p * 4;
        float aR = 0.f, aI = 0.f;
#pragma unroll 8
        for (int i = 0; i < 64; ++i) {
            float2 xv = XsP[n * 64 + i];
            float2 wv_ = WsP[i * 64 + o];
            aR += xv.x * wv_.x - xv.y * wv_.y;
            aI += xv.x * wv_.y + xv.y * wv_.x;
        }
        X3b[(((size_t)n * 32 + kw) * 64 + khIdx) * 64 + o] = pack2(aR, aI);
    }
}

// ---------------- K4: inverse DFT along h as bf16 MFMA GEMM ----------------
// grid (n,kw,mh,ac) = 1024. A-frags from L2 (A4g). Bs[o][k] swizzled, 16 KB.
__global__ __launch_bounds__(256) void k4_idft_h(const unsigned* __restrict__ X3b,
                                                 const u16* __restrict__ A4g,
                                                 u16* __restrict__ Y1R,
                                                 u16* __restrict__ Y1I) {
    __shared__ __align__(16) u16 Bs[64 * 128];
    int t = threadIdx.x;
    int b = blockIdx.x;
    int n = b >> 7, kw = (b >> 2) & 31, mh = (b >> 1) & 1, ac = b & 1;
    const unsigned* src = X3b + ((size_t)n * 32 + kw) * (64 * 64);
#pragma unroll
    for (int it = 0; it < 16; ++it) {
        int khl = (t & 7) + ((it & 7) << 3);
        int o = ((t >> 3) & 31) + ((it >> 3) << 5);
        unsigned v = src[khl * 64 + o];
        int K = swkey(o) << 3;
        Bs[o * 128 + (khl ^ K)]        = (u16)(v & 0xFFFF);
        Bs[o * 128 + ((64 + khl) ^ K)] = (u16)(v >> 16);
    }
    __syncthreads();
    int wv = t >> 6, l = t & 63, lm = l & 15, lq = l >> 4;
    u16* plane = mh ? Y1I : Y1R;
    f32x4 acc[2][4];
#pragma unroll
    for (int mt = 0; mt < 2; ++mt)
#pragma unroll
        for (int nt = 0; nt < 4; ++nt) { f32x4 z = {0.f, 0.f, 0.f, 0.f}; acc[mt][nt] = z; }
#pragma unroll
    for (int ks = 0; ks < 4; ++ks) {
        short8 a0 = *(const short8*)&A4g[(size_t)(mh * 256 + ac * 128 + wv * 32 + lm) * 128 + ks * 32 + lq * 8];
        short8 a1 = *(const short8*)&A4g[(size_t)(mh * 256 + ac * 128 + wv * 32 + 16 + lm) * 128 + ks * 32 + lq * 8];
#pragma unroll
        for (int nt = 0; nt < 4; ++nt) {
            int c = nt * 16 + lm;
            short8 bfr = *(const short8*)&Bs[c * 128 + ((ks * 32 + lq * 8) ^ (swkey(c) << 3))];
            acc[0][nt] = __builtin_amdgcn_mfma_f32_16x16x32_bf16(a0, bfr, acc[0][nt], 0, 0, 0);
            acc[1][nt] = __builtin_amdgcn_mfma_f32_16x16x32_bf16(a1, bfr, acc[1][nt], 0, 0, 0);
        }
    }
#pragma unroll
    for (int mt = 0; mt < 2; ++mt)
#pragma unroll
        for (int nt = 0; nt < 4; ++nt)
#pragma unroll
            for (int r = 0; r < 4; ++r) {
                int h = ac * 128 + wv * 32 + mt * 16 + lq * 4 + r;
                int o = nt * 16 + lm;
                plane[(((size_t)n * 256 + h) * 32 + kw) * 64 + o] = f2bf(acc[mt][nt][r]);
            }
}

// ------- K5: fused c2r-synthesis + residual GEMM + bias + SiLU, bf16 MFMA --
// A twiddle cols from L2 (T5g); x cols in Xs (swizzled). B: Y^T + res_w^T in Bs.
__global__ __launch_bounds__(256) void k5_final(const u16* __restrict__ YRp,
                                                const u16* __restrict__ YIp,
                                                const float* __restrict__ x,
                                                const float* __restrict__ res_b,
                                                const u16* __restrict__ T5g,
                                                const u16* __restrict__ RWTg,
                                                float* __restrict__ out) {
    __shared__ __align__(16) u16 Xs[128 * 64];   // 16 KB rows wl, cols c
    __shared__ __align__(16) u16 Bs[64 * 128];   // 16 KB rows o, k
    __shared__ float bs[64];
    unsigned* X32 = (unsigned*)Xs;
    unsigned* B32 = (unsigned*)Bs;
    int t = threadIdx.x;
    int nh = blockIdx.x >> 1, half = blockIdx.x & 1;
    if (t < 64) bs[t] = res_b[t];
    const float* xb = x + ((size_t)nh * 256 + half * 128) * 64;
#pragma unroll
    for (int it = 0; it < 8; ++it) {
        int idx = t + it * 256;
        int wl = idx >> 4, c4 = idx & 15;
        float4 f = *(const float4*)&xb[wl * 64 + c4 * 4];
        uint2 pv; pv.x = pack2(f.x, f.y); pv.y = pack2(f.z, f.w);
        *(uint2*)&X32[wl * 32 + ((2 * c4) ^ (swkey(wl) << 2))] = pv;
    }
    const u16* YR = YRp + (size_t)nh * 2048;
    const u16* YI = YIp + (size_t)nh * 2048;
#pragma unroll
    for (int it = 0; it < 8; ++it) {
        int kw = t >> 3;
        int op = (t & 7) + (it & 3) * 8;
        const u16* P = (it >> 2) ? YI : YR;
        unsigned v = *(const unsigned*)&P[kw * 64 + 2 * op];
        int k = (it >> 2) * 32 + kw;
        int o0 = 2 * op;
        Bs[o0 * 128 + (k ^ (swkey(o0) << 3))]       = (u16)(v & 0xFFFF);
        Bs[(o0 + 1) * 128 + (k ^ (swkey(o0 + 1) << 3))] = (u16)(v >> 16);
    }
#pragma unroll
    for (int it = 0; it < 2; ++it) {
        int idx = t + it * 256;            // 0..511
        int o = idx >> 3, g = idx & 7;
        uint4 v = *(const uint4*)&RWTg[o * 64 + g * 8];
        *(uint4*)&B32[o * 64 + (8 + (g ^ swkey(o))) * 4] = v;
    }
    __syncthreads();
    int wv = t >> 6, l = t & 63, lm = l & 15, lq = l >> 4;
    f32x4 acc[2][4];
#pragma unroll
    for (int mt = 0; mt < 2; ++mt)
#pragma unroll
        for (int nt = 0; nt < 4; ++nt) { f32x4 z = {0.f, 0.f, 0.f, 0.f}; acc[mt][nt] = z; }
#pragma unroll
    for (int ks = 0; ks < 4; ++ks) {
        int r0 = wv * 32 + lm, r1 = r0 + 16;
        short8 a0, a1;
        if (ks < 2) {
            a0 = *(const short8*)&T5g[(half * 128 + r0) * 64 + ks * 32 + lq * 8];
            a1 = *(const short8*)&T5g[(half * 128 + r1) * 64 + ks * 32 + lq * 8];
        } else {
            a0 = *(const short8*)&Xs[r0 * 64 + (((ks - 2) * 32 + lq * 8) ^ (swkey(r0) << 3))];
            a1 = *(const short8*)&Xs[r1 * 64 + (((ks - 2) * 32 + lq * 8) ^ (swkey(r1) << 3))];
        }
#pragma unroll
        for (int nt = 0; nt < 4; ++nt) {
            int c = nt * 16 + lm;
            short8 b = *(const short8*)&Bs[c * 128 + ((ks * 32 + lq * 8) ^ (swkey(c) << 3))];
            acc[0][nt] = __builtin_amdgcn_mfma_f32_16x16x32_bf16(a0, b, acc[0][nt], 0, 0, 0);
            acc[1][nt] = __builtin_amdgcn_mfma_f32_16x16x32_bf16(a1, b, acc[1][nt], 0, 0, 0);
        }
    }
    float* orow = out + ((size_t)nh * 256 + half * 128) * 64;
#pragma unroll
    for (int mt = 0; mt < 2; ++mt)
#pragma unroll
        for (int nt = 0; nt < 4; ++nt)
#pragma unroll
            for (int r = 0; r < 4; ++r) {
                int wloc = wv * 32 + mt * 16 + lq * 4 + r;
                int o = nt * 16 + lm;
                float v = acc[mt][nt][r] + bs[o];
                float sv = v / (1.0f + __expf(-v));
                orow[wloc * 64 + o] = sv;
            }
}

extern "C" void kernel_launch(void* const* d_in, const int* in_sizes, int n_in,
                              void* d_out, int out_size, void* d_ws, size_t ws_size,
                              hipStream_t stream) {
    const float* x     = (const float*)d_in[0];
    const float* w0    = (const float*)d_in[1];
    const float* w1    = (const float*)d_in[2];
    const float* res_w = (const float*)d_in[3];
    const float* res_b = (const float*)d_in[4];
    float* out = (float*)d_out;
    char* ws = (char*)d_ws;
    u16*      X1R  = (u16*)(ws);                    //  8,388,608
    u16*      X1I  = (u16*)(ws + 8388608);          //  8,388,608
    float2*   X2   = (float2*)(ws + 16777216);      //  8,388,608
    unsigned* X3b  = (unsigned*)(ws + 25165824);    //  4,194,304 (bf16 R,I packed)
    u16*      Y1R  = (u16*)(ws + 33554432);         //  8,388,608
    u16*      Y1I  = (u16*)(ws + 41943040);         //  8,388,608
    u16*      A2g  = (u16*)(ws + 50331648);         //    131,072
    u16*      A4g  = (u16*)(ws + 50462720);         //    131,072
    u16*      T1g  = (u16*)(ws + 50593792);         //     32,768
    u16*      T5g  = (u16*)(ws + 50626560);         //     32,768
    u16*      RWTg = (u16*)(ws + 50659328);         //      8,192

    k0_tables  <<<256,          256, 0, stream>>>(A2g, A4g, T1g, T5g, res_w, RWTg);
    k1_dft_w   <<<NN * RR,      256, 0, stream>>>(x, T1g, X1R, X1I);
    k2_dft_h   <<<NN * KWN,     512, 0, stream>>>(X1R, X1I, A2g, X2);
    k3_spectral<<<KHN * KWN,    256, 0, stream>>>(X2, w0, w1, X3b);
    k4_idft_h  <<<NN * KWN * 4, 256, 0, stream>>>(X3b, A4g, Y1R, Y1I);
    k5_final   <<<NN * RR * 2,  256, 0, stream>>>(Y1R, Y1I, x, res_b, T5g, RWTg, out);
}